// Round 7
// baseline (386.941 us; speedup 1.0000x reference)
//
#include <hip/hip_runtime.h>
#include <stdint.h>

#define TT 8192          // sequence length T
#define BT 16384         // B*T tokens
#define MCH 8192         // token chunk for qkv GEMM + attention

typedef __attribute__((ext_vector_type(8))) __bf16 bf16x8;
typedef __attribute__((ext_vector_type(4))) float floatx4;

__device__ __forceinline__ float bf2f(unsigned short h) {
  union { unsigned u; float f; } x; x.u = ((unsigned)h) << 16; return x.f;
}
__device__ __forceinline__ unsigned short f2bf(float f) {
  union { float f; unsigned u; } x; x.f = f;
  unsigned r = (x.u + 0x7fffu + ((x.u >> 16) & 1u)) >> 16;
  return (unsigned short)r;
}
__device__ __forceinline__ void async16(const void* g, void* l) {
  __builtin_amdgcn_global_load_lds(
      (__attribute__((address_space(1))) void*)g,
      (__attribute__((address_space(3))) void*)l, 16, 0, 0);
}

// ---------------------------------------------------------------------------
// fp32 -> bf16 conversion (round-to-nearest-even), float4 vectorized.
// ---------------------------------------------------------------------------
__global__ __launch_bounds__(256) void cvt_f2b(
    const float* __restrict__ src, unsigned short* __restrict__ dst, int n4) {
  const int i = blockIdx.x * 256 + threadIdx.x;
  if (i < n4) {
    const float4 f = ((const float4*)src)[i];
    union { uint2 u2; unsigned short s[4]; } o;
    o.s[0] = f2bf(f.x); o.s[1] = f2bf(f.y);
    o.s[2] = f2bf(f.z); o.s[3] = f2bf(f.w);
    ((uint2*)dst)[i] = o.u2;
  }
}

// ---------------------------------------------------------------------------
// RoPE cos/sin table: tab[t*32+p] = (cos, sin) of t * 10000^(-p/32)
// ---------------------------------------------------------------------------
__global__ __launch_bounds__(256) void rope_table_k(float2* __restrict__ tab) {
  const int i = blockIdx.x * 256 + threadIdx.x;
  if (i < TT * 32) {
    const int t = i >> 5, p = i & 31;
    const float f = (float)t * exp2f((float)p * -0.41524101186092f); // -log2(1e4)/32
    float s, c;
    sincosf(f, &s, &c);
    tab[i] = make_float2(c, s);
  }
}

// ---------------------------------------------------------------------------
// GEMM: C[M,N] = A[M,K] . W[N,K]^T   (bf16 in; bf16 or fp32 out; fp32 accum)
// m97 structure: 128x128 tile, BK=32, 4 waves (2x2), each wave 64x64 via 4x4
// mfma_f32_16x16x32_bf16; staging via global_load_lds width=16 into
// row-major [128][32] bf16 LDS. bf16 epilogue repacks via per-wave LDS slice
// (stride 68, barrier-free) into 16B coalesced stores.
// ---------------------------------------------------------------------------
template <bool CF32>
__global__ __launch_bounds__(256) void gemm_bt(
    const unsigned short* __restrict__ A,
    const unsigned short* __restrict__ W,
    void* __restrict__ C,
    int M, int N, int K)
{
  __shared__ __align__(16) unsigned short As[128 * 32];
  __shared__ __align__(16) unsigned short Bs[128 * 32];
  __shared__ __align__(16) float Ep[4][16 * 68];   // per-wave epilogue slice

  const int tid  = threadIdx.x;
  const int lane = tid & 63;
  const int w    = tid >> 6;
  const int nb   = N / 128;
  const int bm   = blockIdx.x / nb;
  const int bn   = blockIdx.x % nb;
  const int wm   = w & 1;
  const int wn   = w >> 1;
  const int kg   = lane >> 4;     // k-chunk group 0..3 (8 bf16 each)
  const int lm   = lane & 15;
  const int srow = lane >> 2;     // staging: row within 16-row group
  const int sch  = lane & 3;      // staging: 16B chunk within row

  floatx4 acc[4][4];
  floatx4 z = {0.f, 0.f, 0.f, 0.f};
#pragma unroll
  for (int i = 0; i < 4; ++i)
#pragma unroll
    for (int j = 0; j < 4; ++j) acc[i][j] = z;

  const size_t abase = (size_t)(bm * 128) * K;
  const size_t bbase = (size_t)(bn * 128) * K;

  for (int kt = 0; kt < K; kt += 32) {
#pragma unroll
    for (int s2 = 0; s2 < 2; ++s2) {
      const int s   = 2 * w + s2;          // 16-row group 0..7
      const int row = 16 * s + srow;
      async16(A + abase + (size_t)row * K + kt + sch * 8, (char*)As + s * 1024);
      async16(W + bbase + (size_t)row * K + kt + sch * 8, (char*)Bs + s * 1024);
    }
    __syncthreads();

    bf16x8 af[4], bfr[4];
#pragma unroll
    for (int i = 0; i < 4; ++i) {
      const int r = wm * 64 + i * 16 + lm;
      af[i] = *(const bf16x8*)(As + r * 32 + kg * 8);
    }
#pragma unroll
    for (int j = 0; j < 4; ++j) {
      const int r = wn * 64 + j * 16 + lm;
      bfr[j] = *(const bf16x8*)(Bs + r * 32 + kg * 8);
    }
#pragma unroll
    for (int i = 0; i < 4; ++i)
#pragma unroll
      for (int j = 0; j < 4; ++j)
        acc[i][j] = __builtin_amdgcn_mfma_f32_16x16x32_bf16(af[i], bfr[j], acc[i][j], 0, 0, 0);
    __syncthreads();
  }

  // C/D layout: col = lane&15, row = (lane>>4)*4 + reg
  if (CF32) {
#pragma unroll
    for (int i = 0; i < 4; ++i) {
      const int row0 = bm * 128 + wm * 64 + i * 16 + kg * 4;
#pragma unroll
      for (int j = 0; j < 4; ++j) {
        const int col = bn * 128 + wn * 64 + j * 16 + lm;
#pragma unroll
        for (int r = 0; r < 4; ++r)
          ((float*)C)[(size_t)(row0 + r) * N + col] = acc[i][j][r];
      }
    }
  } else {
    // repack through per-wave LDS slice: no barriers (private buffer,
    // per-wave DS ops are in-order).
    float* eb = Ep[w];
#pragma unroll
    for (int i = 0; i < 4; ++i) {
#pragma unroll
      for (int j = 0; j < 4; ++j)
#pragma unroll
        for (int r = 0; r < 4; ++r)
          eb[(kg * 4 + r) * 68 + j * 16 + lm] = acc[i][j][r];
      const int rrow = lm;      // slice row this lane stores
      const int colq = kg;      // 16-col quarter this lane stores
      const float* rp = eb + rrow * 68 + colq * 16;
      const float4 f0 = *(const float4*)(rp + 0);
      const float4 f1 = *(const float4*)(rp + 4);
      const float4 f2 = *(const float4*)(rp + 8);
      const float4 f3 = *(const float4*)(rp + 12);
      union { uint4 u; unsigned short s[8]; } p0, p1;
      p0.s[0] = f2bf(f0.x); p0.s[1] = f2bf(f0.y); p0.s[2] = f2bf(f0.z); p0.s[3] = f2bf(f0.w);
      p0.s[4] = f2bf(f1.x); p0.s[5] = f2bf(f1.y); p0.s[6] = f2bf(f1.z); p0.s[7] = f2bf(f1.w);
      p1.s[0] = f2bf(f2.x); p1.s[1] = f2bf(f2.y); p1.s[2] = f2bf(f2.z); p1.s[3] = f2bf(f2.w);
      p1.s[4] = f2bf(f3.x); p1.s[5] = f2bf(f3.y); p1.s[6] = f2bf(f3.z); p1.s[7] = f2bf(f3.w);
      unsigned short* cp = (unsigned short*)C +
          (size_t)(bm * 128 + wm * 64 + i * 16 + rrow) * N + bn * 128 + wn * 64 + colq * 16;
      *(uint4*)cp       = p0.u;
      *(uint4*)(cp + 8) = p1.u;
    }
  }
}

// ---------------------------------------------------------------------------
// Per-token head-attention with fused RoPE (cos/sin from precomputed table).
// One wave per token (2 tokens / 128-thread block).
// Output written directly in the transpose(0,2,1,3).reshape layout:
//   Y[b*8192 + qh*512 + t/16][(t&15)*64 + d]
// ---------------------------------------------------------------------------
__global__ __launch_bounds__(128) void attn_rope_k(
    const unsigned short* __restrict__ qkv,   // chunk-local, MCH tokens
    const float2* __restrict__ tab,
    unsigned short* __restrict__ Y,
    int base)                                  // global token offset of chunk
{
  __shared__ float sQ[2][16 * 68];
  __shared__ float sK[2][16 * 68];
  __shared__ float sV[2][16 * 68];
  __shared__ float sP[2][256];   // P^T: [kh*16 + qh]

  const int wave = threadIdx.x >> 6;
  const int lane = threadIdx.x & 63;
  const int ml = blockIdx.x * 2 + wave;  // chunk-local token
  const int m  = base + ml;              // global token
  const int t  = m & (TT - 1);
  const int b  = m >> 13;

  float* Q  = sQ[wave];
  float* Kx = sK[wave];
  float* V  = sV[wave];
  float* P  = sP[wave];

  const uint4* row = (const uint4*)(qkv + (size_t)ml * 3072);
#pragma unroll
  for (int i = 0; i < 6; ++i) {
    const int c = lane + 64 * i;          // chunk of 8 bf16, 0..383
    union { uint4 u4; unsigned short s[8]; } cv;
    cv.u4 = row[c];
    float f[8];
#pragma unroll
    for (int j = 0; j < 8; ++j) f[j] = bf2f(cv.s[j]);
    const int n0   = c * 8;
    const int part = n0 >> 10;            // 0=q 1=k 2=v (uniform per i)
    const int h    = (n0 >> 6) & 15;
    const int d0   = n0 & 63;
    if (part < 2) {
      const int p0 = d0 >> 1;             // multiple of 4
      const float4 csA = *(const float4*)(tab + (t << 5) + p0);      // p0, p0+1
      const float4 csB = *(const float4*)(tab + (t << 5) + p0 + 2);  // p0+2, p0+3
      const float cs[4] = {csA.x, csA.z, csB.x, csB.z};
      const float sn[4] = {csA.y, csA.w, csB.y, csB.w};
#pragma unroll
      for (int j = 0; j < 4; ++j) {
        const float x1 = f[2 * j], x2 = f[2 * j + 1];
        f[2 * j]     = x1 * cs[j] - x2 * sn[j];
        f[2 * j + 1] = x2 * cs[j] + x1 * sn[j];
      }
    }
    float* dst = (part == 0) ? Q : ((part == 1) ? Kx : V);
#pragma unroll
    for (int j = 0; j < 8; ++j) dst[h * 68 + d0 + j] = f[j];
  }
  __syncthreads();

  // scores: lane -> (qh = lane&15, key-group kgp = lane>>4 covering 4 kh)
  const int qh  = lane & 15;
  const int kgp = lane >> 4;
  float s4[4] = {0.f, 0.f, 0.f, 0.f};
  const float* qrow = Q + qh * 68;
#pragma unroll
  for (int d4 = 0; d4 < 64; d4 += 4) {
    const float4 qv = *(const float4*)(qrow + d4);
#pragma unroll
    for (int j = 0; j < 4; ++j) {
      const float4 kv = *(const float4*)(Kx + (kgp * 4 + j) * 68 + d4);
      s4[j] += qv.x * kv.x + qv.y * kv.y + qv.z * kv.z + qv.w * kv.w;
    }
  }
  float mx = -1e30f;
#pragma unroll
  for (int j = 0; j < 4; ++j) { s4[j] *= 0.125f; mx = fmaxf(mx, s4[j]); }
  mx = fmaxf(mx, __shfl_xor(mx, 16, 64));
  mx = fmaxf(mx, __shfl_xor(mx, 32, 64));
  float sum = 0.f;
#pragma unroll
  for (int j = 0; j < 4; ++j) { s4[j] = __expf(s4[j] - mx); sum += s4[j]; }
  sum += __shfl_xor(sum, 16, 64);
  sum += __shfl_xor(sum, 32, 64);
  const float inv = 1.0f / sum;
#pragma unroll
  for (int j = 0; j < 4; ++j) P[(kgp * 4 + j) * 16 + qh] = s4[j] * inv;
  __syncthreads();

  // PV: lane -> (qh, d-group dg = lane>>4, 16 d each)
  const int dg = kgp;
  float o[16];
#pragma unroll
  for (int dd = 0; dd < 16; ++dd) o[dd] = 0.f;
#pragma unroll
  for (int kh = 0; kh < 16; ++kh) {
    const float a = P[kh * 16 + qh];
    const float* vr = V + kh * 68 + dg * 16;
#pragma unroll
    for (int dd = 0; dd < 16; dd += 4) {
      const float4 vv = *(const float4*)(vr + dd);
      o[dd]     += a * vv.x;
      o[dd + 1] += a * vv.y;
      o[dd + 2] += a * vv.z;
      o[dd + 3] += a * vv.w;
    }
  }
  const size_t r = (size_t)b * TT + (size_t)qh * 512 + (t >> 4);
  const int col  = (t & 15) * 64 + dg * 16;
  unsigned short* yp = Y + r * 1024 + col;
  union { uint4 u4; unsigned short s[8]; } o1, o2;
#pragma unroll
  for (int dd = 0; dd < 8; ++dd) o1.s[dd] = f2bf(o[dd]);
#pragma unroll
  for (int dd = 0; dd < 8; ++dd) o2.s[dd] = f2bf(o[8 + dd]);
  ((uint4*)yp)[0] = o1.u4;
  ((uint4*)yp)[1] = o2.u4;
}

// ---------------------------------------------------------------------------
extern "C" void kernel_launch(void* const* d_in, const int* in_sizes, int n_in,
                              void* d_out, int out_size, void* d_ws, size_t ws_size,
                              hipStream_t stream) {
  const float* x    = (const float*)d_in[0];  // (2,8192,1024) fp32
  const float* Wqkv = (const float*)d_in[1];  // (3072,1024)  fp32
  const float* Wout = (const float*)d_in[2];  // (1024,1024)  fp32
  float* out = (float*)d_out;                 // (2,8192,1024) fp32

  // ws (56 MiB, proven): Y 32 | Wqkvb 6 | Woutb 2 | xb 16
  // d_out (67.1 MB): qkv chunk 50.3 MB at offset 0, rope table 2 MiB at
  // +52 MiB (both consumed before the final GEMM overwrites d_out).
  unsigned short* Y     = (unsigned short*)d_ws;
  unsigned short* Wqkvb = Y + (size_t)BT * 1024;
  unsigned short* Woutb = Wqkvb + (size_t)3072 * 1024;
  unsigned short* xb    = Woutb + (size_t)1024 * 1024;
  unsigned short* qkvC  = (unsigned short*)d_out;
  float2* tab           = (float2*)((char*)d_out + (size_t)52 * 1024 * 1024);

  rope_table_k<<<dim3(TT * 32 / 256), dim3(256), 0, stream>>>(tab);
  cvt_f2b<<<dim3(3072 * 1024 / 4 / 256), dim3(256), 0, stream>>>(Wqkv, Wqkvb, 3072 * 1024 / 4);
  cvt_f2b<<<dim3(1024 * 1024 / 4 / 256), dim3(256), 0, stream>>>(Wout, Woutb, 1024 * 1024 / 4);

  for (int base = 0; base < BT; base += MCH) {
    cvt_f2b<<<dim3(MCH * 1024 / 4 / 256), dim3(256), 0, stream>>>(
        x + (size_t)base * 1024, xb, MCH * 1024 / 4);
    gemm_bt<false><<<dim3((MCH / 128) * (3072 / 128)), dim3(256), 0, stream>>>(
        xb, Wqkvb, qkvC, MCH, 3072, 1024);
    attn_rope_k<<<dim3(MCH / 2), dim3(128), 0, stream>>>(qkvC, tab, Y, base);
  }

  // out = Y @ Wout^T : M=16384, N=1024, K=1024 (fp32 output)
  gemm_bt<true><<<dim3((BT / 128) * (1024 / 128)), dim3(256), 0, stream>>>(
      Y, Woutb, out, BT, 1024, 1024);
}

// Round 8
// 361.245 us; speedup vs baseline: 1.0711x; 1.0711x over previous
//
#include <hip/hip_runtime.h>
#include <stdint.h>

#define TT 8192          // sequence length T
#define BT 16384         // B*T tokens
#define MCH 8192         // token chunk for qkv GEMM + attention

typedef __attribute__((ext_vector_type(8))) __bf16 bf16x8;
typedef __attribute__((ext_vector_type(4))) __bf16 bf16x4;
typedef __attribute__((ext_vector_type(4))) short short4v;
typedef __attribute__((ext_vector_type(4))) float floatx4;

__device__ __forceinline__ float bf2f(unsigned short h) {
  union { unsigned u; float f; } x; x.u = ((unsigned)h) << 16; return x.f;
}
__device__ __forceinline__ unsigned short f2bf(float f) {
  union { float f; unsigned u; } x; x.f = f;
  unsigned r = (x.u + 0x7fffu + ((x.u >> 16) & 1u)) >> 16;
  return (unsigned short)r;
}
__device__ __forceinline__ void async16(const void* g, void* l) {
  __builtin_amdgcn_global_load_lds(
      (__attribute__((address_space(1))) void*)g,
      (__attribute__((address_space(3))) void*)l, 16, 0, 0);
}

// ---------------------------------------------------------------------------
// fp32 -> bf16 conversion (round-to-nearest-even), float4 vectorized.
// ---------------------------------------------------------------------------
__global__ __launch_bounds__(256) void cvt_f2b(
    const float* __restrict__ src, unsigned short* __restrict__ dst, int n4) {
  const int i = blockIdx.x * 256 + threadIdx.x;
  if (i < n4) {
    const float4 f = ((const float4*)src)[i];
    union { uint2 u2; unsigned short s[4]; } o;
    o.s[0] = f2bf(f.x); o.s[1] = f2bf(f.y);
    o.s[2] = f2bf(f.z); o.s[3] = f2bf(f.w);
    ((uint2*)dst)[i] = o.u2;
  }
}

// ---------------------------------------------------------------------------
// RoPE cos/sin table: tab[t*32+p] = (cos, sin) of t * 10000^(-p/32)
// ---------------------------------------------------------------------------
__global__ __launch_bounds__(256) void rope_table_k(float2* __restrict__ tab) {
  const int i = blockIdx.x * 256 + threadIdx.x;
  if (i < TT * 32) {
    const int t = i >> 5, p = i & 31;
    const float f = (float)t * exp2f((float)p * -0.41524101186092f); // -log2(1e4)/32
    float s, c;
    sincosf(f, &s, &c);
    tab[i] = make_float2(c, s);
  }
}

// ---------------------------------------------------------------------------
// GEMM (round-6 exact): C[M,N] = A[M,K] . W[N,K]^T  (bf16 in; bf16/fp32 out)
// 128x128 tile, BK=32, 4 waves (2x2), 4x4 mfma_f32_16x16x32_bf16,
// global_load_lds width=16 staging into row-major [128][32] bf16 LDS.
// ---------------------------------------------------------------------------
template <bool CF32>
__global__ __launch_bounds__(256) void gemm_bt(
    const unsigned short* __restrict__ A,
    const unsigned short* __restrict__ W,
    void* __restrict__ C,
    int M, int N, int K)
{
  __shared__ __align__(16) unsigned short As[128 * 32];
  __shared__ __align__(16) unsigned short Bs[128 * 32];

  const int tid  = threadIdx.x;
  const int lane = tid & 63;
  const int w    = tid >> 6;
  const int nb   = N / 128;
  const int bm   = blockIdx.x / nb;
  const int bn   = blockIdx.x % nb;
  const int wm   = w & 1;
  const int wn   = w >> 1;
  const int kg   = lane >> 4;
  const int lm   = lane & 15;
  const int srow = lane >> 2;
  const int sch  = lane & 3;

  floatx4 acc[4][4];
  floatx4 z = {0.f, 0.f, 0.f, 0.f};
#pragma unroll
  for (int i = 0; i < 4; ++i)
#pragma unroll
    for (int j = 0; j < 4; ++j) acc[i][j] = z;

  const size_t abase = (size_t)(bm * 128) * K;
  const size_t bbase = (size_t)(bn * 128) * K;

  for (int kt = 0; kt < K; kt += 32) {
#pragma unroll
    for (int s2 = 0; s2 < 2; ++s2) {
      const int s   = 2 * w + s2;
      const int row = 16 * s + srow;
      async16(A + abase + (size_t)row * K + kt + sch * 8, (char*)As + s * 1024);
      async16(W + bbase + (size_t)row * K + kt + sch * 8, (char*)Bs + s * 1024);
    }
    __syncthreads();

    bf16x8 af[4], bfr[4];
#pragma unroll
    for (int i = 0; i < 4; ++i) {
      const int r = wm * 64 + i * 16 + lm;
      af[i] = *(const bf16x8*)(As + r * 32 + kg * 8);
    }
#pragma unroll
    for (int j = 0; j < 4; ++j) {
      const int r = wn * 64 + j * 16 + lm;
      bfr[j] = *(const bf16x8*)(Bs + r * 32 + kg * 8);
    }
#pragma unroll
    for (int i = 0; i < 4; ++i)
#pragma unroll
      for (int j = 0; j < 4; ++j)
        acc[i][j] = __builtin_amdgcn_mfma_f32_16x16x32_bf16(af[i], bfr[j], acc[i][j], 0, 0, 0);
    __syncthreads();
  }

#pragma unroll
  for (int i = 0; i < 4; ++i) {
    const int row0 = bm * 128 + wm * 64 + i * 16 + kg * 4;
#pragma unroll
    for (int j = 0; j < 4; ++j) {
      const int col = bn * 128 + wn * 64 + j * 16 + lm;
#pragma unroll
      for (int r = 0; r < 4; ++r) {
        if (CF32)
          ((float*)C)[(size_t)(row0 + r) * N + col] = acc[i][j][r];
        else
          ((unsigned short*)C)[(size_t)(row0 + r) * N + col] = f2bf(acc[i][j][r]);
      }
    }
  }
}

// ---------------------------------------------------------------------------
// MFMA-based per-token head-attention with fused RoPE (table-based).
// One wave per token (2 tokens / 128-thread block). Q/K/V staged as bf16
// rows [16][72] (b128 writes, conflict-free). Scores: S^T = K.Q^T via
// 2x mfma_16x16x32_bf16 -> s4[r] = S[lm][quad*4+r] (same softmax layout as
// before). PV via mfma_16x16x16_bf16 (P packed in-register; S^T C-layout ==
// P A-layout, no transform) or lean VALU fallback.
// Output in transpose(0,2,1,3).reshape layout:
//   Y[b*8192 + qh*512 + t/16][(t&15)*64 + d]
// ---------------------------------------------------------------------------
#if defined(__has_builtin)
#if __has_builtin(__builtin_amdgcn_mfma_f32_16x16x16_bf16)
#define PV_MFMA 1
#define PV_MFMA_CALL(a, b, c) __builtin_amdgcn_mfma_f32_16x16x16_bf16( \
    *(bf16x4*)&(a), *(bf16x4*)&(b), (c), 0, 0, 0)
#elif __has_builtin(__builtin_amdgcn_mfma_f32_16x16x16bf16_1k)
#define PV_MFMA 1
#define PV_MFMA_CALL(a, b, c) __builtin_amdgcn_mfma_f32_16x16x16bf16_1k( \
    (a), (b), (c), 0, 0, 0)
#else
#define PV_MFMA 0
#endif
#else
#define PV_MFMA 0
#endif

__global__ __launch_bounds__(128) void attn_rope_k(
    const unsigned short* __restrict__ qkv,   // chunk-local, MCH tokens
    const float2* __restrict__ tab,
    unsigned short* __restrict__ Y,
    int base)
{
  // per-wave: Q [16][72], K [16][72], V [16][72] bf16 (pad 8 per row)
  __shared__ __align__(16) unsigned short sQKV[2][3 * 16 * 72];
#if !PV_MFMA
  __shared__ float sP[2][256];
#endif

  const int wave = threadIdx.x >> 6;
  const int lane = threadIdx.x & 63;
  const int ml = blockIdx.x * 2 + wave;  // chunk-local token
  const int m  = base + ml;              // global token
  const int t  = m & (TT - 1);
  const int b  = m >> 13;

  unsigned short* QB = sQKV[wave];            // Q rows
  unsigned short* KB = QB + 16 * 72;          // K rows
  unsigned short* VB = QB + 2 * 16 * 72;      // V rows

  const int lm   = lane & 15;
  const int quad = lane >> 4;

  // ---- staging: 6 x (b128 global read -> rope -> b128 LDS write) ----
  const uint4* row = (const uint4*)(qkv + (size_t)ml * 3072);
#pragma unroll
  for (int i = 0; i < 6; ++i) {
    const int c = lane + 64 * i;          // chunk of 8 bf16
    union { uint4 u4; unsigned short s[8]; } cv;
    cv.u4 = row[c];
    const int n0   = c * 8;
    const int part = n0 >> 10;            // 0=q 1=k 2=v (uniform per i)
    const int h    = (n0 >> 6) & 15;
    const int d0   = n0 & 63;
    if (part < 2) {
      float f[8];
#pragma unroll
      for (int j = 0; j < 8; ++j) f[j] = bf2f(cv.s[j]);
      const int p0 = d0 >> 1;
      const float4 csA = *(const float4*)(tab + (t << 5) + p0);
      const float4 csB = *(const float4*)(tab + (t << 5) + p0 + 2);
      const float cs[4] = {csA.x, csA.z, csB.x, csB.z};
      const float sn[4] = {csA.y, csA.w, csB.y, csB.w};
#pragma unroll
      for (int j = 0; j < 4; ++j) {
        const float x1 = f[2 * j], x2 = f[2 * j + 1];
        cv.s[2 * j]     = f2bf(x1 * cs[j] - x2 * sn[j]);
        cv.s[2 * j + 1] = f2bf(x2 * cs[j] + x1 * sn[j]);
      }
    }
    unsigned short* dst = QB + part * (16 * 72) + h * 72 + d0;
    *(uint4*)dst = cv.u4;
  }
  __syncthreads();

  // ---- scores: S^T = K . Q^T via 2x mfma_16x16x32 ----
  floatx4 accS = {0.f, 0.f, 0.f, 0.f};
#pragma unroll
  for (int half = 0; half < 2; ++half) {
    const bf16x8 kf = *(const bf16x8*)(KB + lm * 72 + half * 32 + quad * 8);
    const bf16x8 qf = *(const bf16x8*)(QB + lm * 72 + half * 32 + quad * 8);
    accS = __builtin_amdgcn_mfma_f32_16x16x32_bf16(kf, qf, accS, 0, 0, 0);
  }
  // accS[r] = S[q=lm][k=quad*4+r]
  float s4[4];
  float mx = -1e30f;
#pragma unroll
  for (int j = 0; j < 4; ++j) { s4[j] = accS[j] * 0.125f; mx = fmaxf(mx, s4[j]); }
  mx = fmaxf(mx, __shfl_xor(mx, 16, 64));
  mx = fmaxf(mx, __shfl_xor(mx, 32, 64));
  float sum = 0.f;
#pragma unroll
  for (int j = 0; j < 4; ++j) { s4[j] = __expf(s4[j] - mx); sum += s4[j]; }
  sum += __shfl_xor(sum, 16, 64);
  sum += __shfl_xor(sum, 32, 64);
  const float inv = 1.0f / sum;

#if PV_MFMA
  // ---- PV via mfma_16x16x16: A = P (in-register, S^T C-layout == A-layout)
  union { short4v v; unsigned short s[4]; } pf;
#pragma unroll
  for (int j = 0; j < 4; ++j) pf.s[j] = s4[j] * inv == 0.f ? 0 : f2bf(s4[j] * inv);
  // O[q=quad*4+r][dtile*16+lm]
#pragma unroll
  for (int dtile = 0; dtile < 4; ++dtile) {
    union { short4v v; unsigned short s[4]; } vf;
#pragma unroll
    for (int j = 0; j < 4; ++j)
      vf.s[j] = VB[(quad * 4 + j) * 72 + dtile * 16 + lm];
    floatx4 accO = {0.f, 0.f, 0.f, 0.f};
    accO = PV_MFMA_CALL(pf.v, vf.v, accO);
    const int col = (t & 15) * 64 + dtile * 16 + lm;
#pragma unroll
    for (int r = 0; r < 4; ++r) {
      const size_t rr = (size_t)b * TT + (size_t)(quad * 4 + r) * 512 + (t >> 4);
      Y[rr * 1024 + col] = f2bf(accO[r]);
    }
  }
#else
  // ---- VALU fallback: P via small LDS, V read as bf16 b128 ----
  float* P = sP[wave];
#pragma unroll
  for (int j = 0; j < 4; ++j) P[(quad * 4 + j) * 16 + lm] = s4[j] * inv;
  __syncthreads();
  float o[16];
#pragma unroll
  for (int dd = 0; dd < 16; ++dd) o[dd] = 0.f;
#pragma unroll
  for (int kh = 0; kh < 16; ++kh) {
    const float a = P[kh * 16 + lm];
    union { uint4 u4; unsigned short s[8]; } v0, v1;
    v0.u4 = *(const uint4*)(VB + kh * 72 + quad * 16);
    v1.u4 = *(const uint4*)(VB + kh * 72 + quad * 16 + 8);
#pragma unroll
    for (int dd = 0; dd < 8; ++dd) {
      o[dd]     += a * bf2f(v0.s[dd]);
      o[dd + 8] += a * bf2f(v1.s[dd]);
    }
  }
  const size_t rr = (size_t)b * TT + (size_t)lm * 512 + (t >> 4);
  unsigned short* yp = Y + rr * 1024 + (t & 15) * 64 + quad * 16;
  union { uint4 u4; unsigned short s[8]; } o1, o2;
#pragma unroll
  for (int dd = 0; dd < 8; ++dd) o1.s[dd] = f2bf(o[dd]);
#pragma unroll
  for (int dd = 0; dd < 8; ++dd) o2.s[dd] = f2bf(o[8 + dd]);
  ((uint4*)yp)[0] = o1.u4;
  ((uint4*)yp)[1] = o2.u4;
#endif
}

// ---------------------------------------------------------------------------
extern "C" void kernel_launch(void* const* d_in, const int* in_sizes, int n_in,
                              void* d_out, int out_size, void* d_ws, size_t ws_size,
                              hipStream_t stream) {
  const float* x    = (const float*)d_in[0];  // (2,8192,1024) fp32
  const float* Wqkv = (const float*)d_in[1];  // (3072,1024)  fp32
  const float* Wout = (const float*)d_in[2];  // (1024,1024)  fp32
  float* out = (float*)d_out;                 // (2,8192,1024) fp32

  // ws (56 MiB, proven): Y 32 | Wqkvb 6 | Woutb 2 | xb 16
  // d_out (67.1 MB): qkv chunk 50.3 MB at 0, rope table 2 MiB at +52 MiB.
  unsigned short* Y     = (unsigned short*)d_ws;
  unsigned short* Wqkvb = Y + (size_t)BT * 1024;
  unsigned short* Woutb = Wqkvb + (size_t)3072 * 1024;
  unsigned short* xb    = Woutb + (size_t)1024 * 1024;
  unsigned short* qkvC  = (unsigned short*)d_out;
  float2* tab           = (float2*)((char*)d_out + (size_t)52 * 1024 * 1024);

  rope_table_k<<<dim3(TT * 32 / 256), dim3(256), 0, stream>>>(tab);
  cvt_f2b<<<dim3(3072 * 1024 / 4 / 256), dim3(256), 0, stream>>>(Wqkv, Wqkvb, 3072 * 1024 / 4);
  cvt_f2b<<<dim3(1024 * 1024 / 4 / 256), dim3(256), 0, stream>>>(Wout, Woutb, 1024 * 1024 / 4);

  for (int base = 0; base < BT; base += MCH) {
    cvt_f2b<<<dim3(MCH * 1024 / 4 / 256), dim3(256), 0, stream>>>(
        x + (size_t)base * 1024, xb, MCH * 1024 / 4);
    gemm_bt<false><<<dim3((MCH / 128) * (3072 / 128)), dim3(256), 0, stream>>>(
        xb, Wqkvb, qkvC, MCH, 3072, 1024);
    attn_rope_k<<<dim3(MCH / 2), dim3(128), 0, stream>>>(qkvC, tab, Y, base);
  }

  // out = Y @ Wout^T : M=16384, N=1024, K=1024 (fp32 output)
  gemm_bt<true><<<dim3((BT / 128) * (1024 / 128)), dim3(256), 0, stream>>>(
      Y, Woutb, out, BT, 1024, 1024);
}